// Round 1
// 92.341 us; speedup vs baseline: 1.0145x; 1.0145x over previous
//
#include <hip/hip_runtime.h>
#include <stdint.h>

#define N1v 1024
#define NNv 2048

typedef float v2f __attribute__((ext_vector_type(2)));

// Kernel A: h = relu(x@W1 + b1) -> fp32 d_out;
//           uT[k][n] = (h[n]@W2)[k] + (n<N1 ? b2[k] : 0)  (k-major fp32 in d_ws)
// 16 nodes/block (grid 128): 4x fewer W2 stagings than 4 nodes/block.
__global__ __launch_bounds__(256) void node_kernel(
    const float* __restrict__ x,    // [2048,6]
    const float* __restrict__ W1,   // [6,64]
    const float* __restrict__ b1,   // [64]
    const float* __restrict__ W2,   // [64,64]
    const float* __restrict__ b2,   // [64]
    float* __restrict__ h_out,      // [2048,64]
    float* __restrict__ uT)         // [64][2048]
{
    __shared__ float hs[16][64];
    __shared__ float w2s[64 * 64];   // [m][k]
    const int t  = threadIdx.x;
    const int nl = t >> 6;          // wave id 0..3
    const int k  = t & 63;
    const int base = blockIdx.x * 16;

    // stage W2 -> LDS (coalesced float4, 4 per thread)
    {
        const float4* w2p = (const float4*)W2;
        float4* w2d = (float4*)w2s;
        #pragma unroll
        for (int q = 0; q < 4; ++q) w2d[q * 256 + t] = w2p[q * 256 + t];
    }

    // phase 1: 4 nodes per wave; x row broadcast across the wave's 64 lanes
    const float2* xp = (const float2*)x;
    #pragma unroll
    for (int q = 0; q < 4; ++q) {
        int nloc = nl * 4 + q;
        int n = base + nloc;
        float2 x0 = xp[n * 3 + 0], x1 = xp[n * 3 + 1], x2 = xp[n * 3 + 2];
        float xv[6] = { x0.x, x0.y, x1.x, x1.y, x2.x, x2.y };
        float acc = b1[k];
        #pragma unroll
        for (int d = 0; d < 6; ++d) acc += xv[d] * W1[d * 64 + k];
        float h = fmaxf(acc, 0.0f);
        h_out[n * 64 + k] = h;       // coalesced
        hs[nloc][k] = h;             // conflict-free
    }
    __syncthreads();

    // phase 2: u = h @ W2 (+ b2 for src-frame nodes). Block is entirely one frame
    // (16 | 1024), so the b2 predicate is block-uniform.
    const float b2v = (blockIdx.x < 64) ? b2[k] : 0.0f;
    float acc2[4] = { b2v, b2v, b2v, b2v };
    #pragma unroll 4
    for (int m4 = 0; m4 < 16; ++m4) {
        int m = m4 * 4;
        float w0 = w2s[(m + 0) * 64 + k];
        float w1 = w2s[(m + 1) * 64 + k];
        float w2v = w2s[(m + 2) * 64 + k];
        float w3v = w2s[(m + 3) * 64 + k];
        #pragma unroll
        for (int q = 0; q < 4; ++q) {
            float4 hv = *(const float4*)&hs[nl * 4 + q][m];   // broadcast b128
            acc2[q] += hv.x * w0 + hv.y * w1 + hv.z * w2v + hv.w * w3v;
        }
    }
    #pragma unroll
    for (int q = 0; q < 4; ++q)
        uT[k * NNv + base + nl * 4 + q] = acc2[q];   // 512KB total, L2-absorbed
}

// Kernel B: scores[i][j][c] = relu(uS[i]-uD[j]) @ W3 + b3
// block tile: 32 i x 64 j (unchanged); NOW 512 threads, thread tile 1 i x 4 j.
// Same staging traffic and store pattern as before, but 8 waves/block ->
// 2 blocks/CU resident -> 4 waves/SIMD (was 2): 2x latency hiding for the
// ds_read -> v_pk chain. Inner math packed 2-wide (v_pk_* on gfx950).
__global__ __launch_bounds__(512, 4) void edge_kernel(
    const float* __restrict__ uT,   // [64][2048] (d_ws)
    const float* __restrict__ W3,   // [64,3]
    const float* __restrict__ b3,   // [3]
    float* __restrict__ out_s)      // [1024,1024,3]
{
    __shared__ float uS_l[64 * 32];   // [k][ii]
    __shared__ float uD_l[64 * 64];   // [k][jj]
    __shared__ float w3s[64 * 4];     // [k][c], padded to 4

    const int t  = threadIdx.x;
    const int i0 = blockIdx.x * 32;
    const int j0 = blockIdx.y * 64;

    {   // uS: 512 float4, one per thread, coalesced
        int kk = t >> 3;
        int i4 = (t & 7) << 2;
        *(float4*)&uS_l[kk * 32 + i4] = *(const float4*)&uT[kk * NNv + i0 + i4];
    }
    #pragma unroll
    for (int p = 0; p < 2; ++p) {     // uD: 1024 float4, two per thread
        int idx = p * 512 + t;
        int kk = idx >> 4;
        int j4 = (idx & 15) << 2;
        *(float4*)&uD_l[kk * 64 + j4] = *(const float4*)&uT[kk * NNv + N1v + j0 + j4];
    }
    if (t < 64) {
        w3s[t * 4 + 0] = W3[t * 3 + 0];
        w3s[t * 4 + 1] = W3[t * 3 + 1];
        w3s[t * 4 + 2] = W3[t * 3 + 2];
        w3s[t * 4 + 3] = 0.0f;
    }
    const float b3v0 = b3[0], b3v1 = b3[1], b3v2 = b3[2];
    __syncthreads();

    const int tx = t & 15;    // j group (4 j's)
    const int ty = t >> 4;    // i row, 0..31

    // accp[p][c]: p = j-pair (x -> j=4tx+2p, y -> j=4tx+2p+1), c = channel
    v2f accp[2][3];
    accp[0][0] = (v2f){b3v0, b3v0}; accp[1][0] = (v2f){b3v0, b3v0};
    accp[0][1] = (v2f){b3v1, b3v1}; accp[1][1] = (v2f){b3v1, b3v1};
    accp[0][2] = (v2f){b3v2, b3v2}; accp[1][2] = (v2f){b3v2, b3v2};
    const v2f vzero = {0.0f, 0.0f};

    #pragma unroll 4
    for (int k = 0; k < 64; ++k) {
        float us  = uS_l[k * 32 + ty];                        // b32, 16-lane broadcast
        float4 ud = *(const float4*)&uD_l[k * 64 + tx * 4];   // 2-way, free
        float4 w3 = *(const float4*)&w3s[k * 4];              // full broadcast
        v2f ud01 = {ud.x, ud.y}, ud23 = {ud.z, ud.w};
        v2f w3x = {w3.x, w3.x}, w3y = {w3.y, w3.y}, w3z = {w3.z, w3.z};
        v2f usa = {us, us};
        v2f d01 = __builtin_elementwise_max(usa - ud01, vzero);
        v2f d23 = __builtin_elementwise_max(usa - ud23, vzero);
        accp[0][0] += d01 * w3x;
        accp[0][1] += d01 * w3y;
        accp[0][2] += d01 * w3z;
        accp[1][0] += d23 * w3x;
        accp[1][1] += d23 * w3y;
        accp[1][2] += d23 * w3z;
    }

    // epilogue: 4 j x 3 ch = 12 floats = 3 aligned float4 stores
    int i = i0 + ty;
    int j = j0 + tx * 4;
    float4* p = (float4*)(out_s + ((size_t)i * 1024 + j) * 3);
    // j0:(c0,c1,c2) j1:(c0,c1,c2) j2:(c0,c1,c2) j3:(c0,c1,c2)
    p[0] = make_float4(accp[0][0].x, accp[0][1].x, accp[0][2].x,
                       accp[0][0].y);
    p[1] = make_float4(accp[0][1].y, accp[0][2].y,
                       accp[1][0].x, accp[1][1].x);
    p[2] = make_float4(accp[1][2].x,
                       accp[1][0].y, accp[1][1].y, accp[1][2].y);
}

extern "C" void kernel_launch(void* const* d_in, const int* in_sizes, int n_in,
                              void* d_out, int out_size, void* d_ws, size_t ws_size,
                              hipStream_t stream) {
    const float* x  = (const float*)d_in[0];
    const float* W1 = (const float*)d_in[1];
    const float* b1 = (const float*)d_in[2];
    const float* W2 = (const float*)d_in[3];
    const float* b2 = (const float*)d_in[4];
    const float* W3 = (const float*)d_in[5];
    const float* b3 = (const float*)d_in[6];
    // d_in[7] edge_index (dense bipartite by construction), d_in[8]/[9] node counts

    float* h_out = (float*)d_out;                  // [2048,64]
    float* s_out = h_out + (size_t)NNv * 64;       // [1024,1024,3]
    float* uT    = (float*)d_ws;                   // 512 KB

    hipLaunchKernelGGL(node_kernel, dim3(128), dim3(256), 0, stream,
                       x, W1, b1, W2, b2, h_out, uT);
    hipLaunchKernelGGL(edge_kernel, dim3(32, 16), dim3(512), 0, stream,
                       uT, W3, b3, s_out);
}

// Round 2
// 90.205 us; speedup vs baseline: 1.0386x; 1.0237x over previous
//
#include <hip/hip_runtime.h>
#include <stdint.h>

#define N1v 1024
#define NNv 2048

typedef float v2f __attribute__((ext_vector_type(2)));

// Kernel A: h = relu(x@W1 + b1) -> fp32 d_out;
//           uT[k][n] = (h[n]@W2)[k] + (n<N1 ? b2[k] : 0)  (k-major fp32 in d_ws)
// 16 nodes/block (grid 128): 4x fewer W2 stagings than 4 nodes/block.
__global__ __launch_bounds__(256) void node_kernel(
    const float* __restrict__ x,    // [2048,6]
    const float* __restrict__ W1,   // [6,64]
    const float* __restrict__ b1,   // [64]
    const float* __restrict__ W2,   // [64,64]
    const float* __restrict__ b2,   // [64]
    float* __restrict__ h_out,      // [2048,64]
    float* __restrict__ uT)         // [64][2048]
{
    __shared__ float hs[16][64];
    __shared__ float w2s[64 * 64];   // [m][k]
    const int t  = threadIdx.x;
    const int nl = t >> 6;          // wave id 0..3
    const int k  = t & 63;
    const int base = blockIdx.x * 16;

    // stage W2 -> LDS (coalesced float4, 4 per thread)
    {
        const float4* w2p = (const float4*)W2;
        float4* w2d = (float4*)w2s;
        #pragma unroll
        for (int q = 0; q < 4; ++q) w2d[q * 256 + t] = w2p[q * 256 + t];
    }

    // phase 1: 4 nodes per wave; x row broadcast across the wave's 64 lanes
    const float2* xp = (const float2*)x;
    #pragma unroll
    for (int q = 0; q < 4; ++q) {
        int nloc = nl * 4 + q;
        int n = base + nloc;
        float2 x0 = xp[n * 3 + 0], x1 = xp[n * 3 + 1], x2 = xp[n * 3 + 2];
        float xv[6] = { x0.x, x0.y, x1.x, x1.y, x2.x, x2.y };
        float acc = b1[k];
        #pragma unroll
        for (int d = 0; d < 6; ++d) acc += xv[d] * W1[d * 64 + k];
        float h = fmaxf(acc, 0.0f);
        h_out[n * 64 + k] = h;       // coalesced
        hs[nloc][k] = h;             // conflict-free
    }
    __syncthreads();

    // phase 2: u = h @ W2 (+ b2 for src-frame nodes). Block is entirely one frame
    // (16 | 1024), so the b2 predicate is block-uniform.
    const float b2v = (blockIdx.x < 64) ? b2[k] : 0.0f;
    float acc2[4] = { b2v, b2v, b2v, b2v };
    #pragma unroll 4
    for (int m4 = 0; m4 < 16; ++m4) {
        int m = m4 * 4;
        float w0 = w2s[(m + 0) * 64 + k];
        float w1 = w2s[(m + 1) * 64 + k];
        float w2v = w2s[(m + 2) * 64 + k];
        float w3v = w2s[(m + 3) * 64 + k];
        #pragma unroll
        for (int q = 0; q < 4; ++q) {
            float4 hv = *(const float4*)&hs[nl * 4 + q][m];   // broadcast b128
            acc2[q] += hv.x * w0 + hv.y * w1 + hv.z * w2v + hv.w * w3v;
        }
    }
    #pragma unroll
    for (int q = 0; q < 4; ++q)
        uT[k * NNv + base + nl * 4 + q] = acc2[q];   // 512KB total, L2-absorbed
}

// Kernel B: scores[i][j][c] = relu(uS[i]-uD[j]) @ W3 + b3
// block tile 32 i x 64 j, 512 threads, thread tile 1 i x 4 j.
// LDS-instruction-bound fix: batch 4 k per iteration.
//   uS transposed [i][k] (stride 68) -> one b128 covers 4 k  (was 4x b32)
//   W3 transposed [c][k]             -> 3 b128 per 4 k       (was 4x b128)
//   uD stays [k][j]                  -> 4 b128 per 4 k
// 8 LDS insts / 4k / thread vs 12 before (-33% on the bottleneck pipe).
__global__ __launch_bounds__(512, 4) void edge_kernel(
    const float* __restrict__ uT,   // [64][2048] (d_ws)
    const float* __restrict__ W3,   // [64,3]
    const float* __restrict__ b3,   // [3]
    float* __restrict__ out_s)      // [1024,1024,3]
{
    __shared__ float uS_l[32 * 68];   // [i][k], stride 68 (16B-aligned at k%4==0,
                                      // 17*i mod 32 spreads the 4 per-wave rows)
    __shared__ float uD_l[64 * 64];   // [k][j]
    __shared__ float w3t[3 * 64];     // [c][k]

    const int t  = threadIdx.x;
    const int i0 = blockIdx.x * 32;
    const int j0 = blockIdx.y * 64;

    {   // uS: coalesced float4 read from uT row, transpose-scatter into [i][k]
        int kk = t >> 3;              // 0..63
        int i4 = (t & 7) << 2;        // 0,4,...,28
        float4 v = *(const float4*)&uT[kk * NNv + i0 + i4];
        uS_l[(i4 + 0) * 68 + kk] = v.x;
        uS_l[(i4 + 1) * 68 + kk] = v.y;
        uS_l[(i4 + 2) * 68 + kk] = v.z;
        uS_l[(i4 + 3) * 68 + kk] = v.w;
    }
    #pragma unroll
    for (int p = 0; p < 2; ++p) {     // uD: 1024 float4, two per thread, coalesced
        int idx = p * 512 + t;
        int kk = idx >> 4;
        int j4 = (idx & 15) << 2;
        *(float4*)&uD_l[kk * 64 + j4] = *(const float4*)&uT[kk * NNv + N1v + j0 + j4];
    }
    if (t < 64) {                     // W3 transposed [c][k]
        w3t[0 * 64 + t] = W3[t * 3 + 0];
        w3t[1 * 64 + t] = W3[t * 3 + 1];
        w3t[2 * 64 + t] = W3[t * 3 + 2];
    }
    const float b3v0 = b3[0], b3v1 = b3[1], b3v2 = b3[2];
    __syncthreads();

    const int tx = t & 15;    // j group (4 j's)
    const int ty = t >> 4;    // i row, 0..31

    // accp[p][c]: p = j-pair (x -> j=4tx+2p, y -> j=4tx+2p+1), c = channel
    v2f accp[2][3];
    accp[0][0] = (v2f){b3v0, b3v0}; accp[1][0] = (v2f){b3v0, b3v0};
    accp[0][1] = (v2f){b3v1, b3v1}; accp[1][1] = (v2f){b3v1, b3v1};
    accp[0][2] = (v2f){b3v2, b3v2}; accp[1][2] = (v2f){b3v2, b3v2};
    const v2f vzero = {0.0f, 0.0f};

    #pragma unroll 2
    for (int k4 = 0; k4 < 64; k4 += 4) {
        float4 us4 = *(const float4*)&uS_l[ty * 68 + k4];   // 4 k's of uS[i]
        float4 w3a = *(const float4*)&w3t[0 * 64 + k4];     // c0, k4..k4+3 (bcast)
        float4 w3b = *(const float4*)&w3t[1 * 64 + k4];     // c1
        float4 w3c = *(const float4*)&w3t[2 * 64 + k4];     // c2
        const float* usp = (const float*)&us4;
        const float* wap = (const float*)&w3a;
        const float* wbp = (const float*)&w3b;
        const float* wcp = (const float*)&w3c;
        #pragma unroll
        for (int q = 0; q < 4; ++q) {
            float4 ud = *(const float4*)&uD_l[(k4 + q) * 64 + tx * 4];
            v2f ud01 = {ud.x, ud.y}, ud23 = {ud.z, ud.w};
            v2f usa = {usp[q], usp[q]};
            v2f w3x = {wap[q], wap[q]};
            v2f w3y = {wbp[q], wbp[q]};
            v2f w3z = {wcp[q], wcp[q]};
            v2f d01 = __builtin_elementwise_max(usa - ud01, vzero);
            v2f d23 = __builtin_elementwise_max(usa - ud23, vzero);
            accp[0][0] += d01 * w3x;
            accp[0][1] += d01 * w3y;
            accp[0][2] += d01 * w3z;
            accp[1][0] += d23 * w3x;
            accp[1][1] += d23 * w3y;
            accp[1][2] += d23 * w3z;
        }
    }

    // epilogue: 4 j x 3 ch = 12 floats = 3 aligned float4 stores
    int i = i0 + ty;
    int j = j0 + tx * 4;
    float4* p = (float4*)(out_s + ((size_t)i * 1024 + j) * 3);
    // j0:(c0,c1,c2) j1:(c0,c1,c2) j2:(c0,c1,c2) j3:(c0,c1,c2)
    p[0] = make_float4(accp[0][0].x, accp[0][1].x, accp[0][2].x,
                       accp[0][0].y);
    p[1] = make_float4(accp[0][1].y, accp[0][2].y,
                       accp[1][0].x, accp[1][1].x);
    p[2] = make_float4(accp[1][2].x,
                       accp[1][0].y, accp[1][1].y, accp[1][2].y);
}

extern "C" void kernel_launch(void* const* d_in, const int* in_sizes, int n_in,
                              void* d_out, int out_size, void* d_ws, size_t ws_size,
                              hipStream_t stream) {
    const float* x  = (const float*)d_in[0];
    const float* W1 = (const float*)d_in[1];
    const float* b1 = (const float*)d_in[2];
    const float* W2 = (const float*)d_in[3];
    const float* b2 = (const float*)d_in[4];
    const float* W3 = (const float*)d_in[5];
    const float* b3 = (const float*)d_in[6];
    // d_in[7] edge_index (dense bipartite by construction), d_in[8]/[9] node counts

    float* h_out = (float*)d_out;                  // [2048,64]
    float* s_out = h_out + (size_t)NNv * 64;       // [1024,1024,3]
    float* uT    = (float*)d_ws;                   // 512 KB

    hipLaunchKernelGGL(node_kernel, dim3(128), dim3(256), 0, stream,
                       x, W1, b1, W2, b2, h_out, uT);
    hipLaunchKernelGGL(edge_kernel, dim3(32, 16), dim3(512), 0, stream,
                       uT, W3, b3, s_out);
}